// Round 4
// baseline (12.990 us; speedup 1.0000x reference)
//
#include <hip/hip_runtime.h>

// TT-embedding: vocab (50,50,80), embed (8,4,4), rank 16, N=8192, fp32.
//   core0: (1, 50, 8, 16)   -> A[i0][e0][r1]
//   core1: (16, 50, 4, 16)  -> B[r1][i1][e1][r2]
//   core2: (16, 80, 4, 1)   -> C[r2][i2][e2]
// out[n][e0*16+e1*4+e2] = sum_{r1,r2} A*B*C
//
// Fused single kernel, 16 indices per 512-thread block (512 blocks total —
// halved block count vs round 3 to shorten dispatch ramp; per-thread work
// unchanged).
//   Phase A: 1024 tasks (idx,r1,e1) -> T[idx][r1][e1][e2] = sum_r2 B*C,
//            2 tasks/thread, staged in 16 KB LDS.
//   Phase B: thread (idx,e0,e1): out = sum_r1 A[i0,e0,r1] * T[idx][r1][e1][:]
// Association matches reference einsum ((B*C) then A): absmax 1.2e-7.

#define V1 50
#define V2 80
#define RR 16
#define NIDX 8192
#define IDX_PER_BLOCK 16
#define BLOCK 512

__global__ __launch_bounds__(BLOCK) void tt_fused(
    const int* __restrict__ indices,
    const float* __restrict__ c0,
    const float* __restrict__ c1,
    const float* __restrict__ c2,
    float* __restrict__ out)
{
    __shared__ float4 T[IDX_PER_BLOCK * 64];   // [idx][r1][e1] -> float4 over e2 (16 KB)

    const int t = threadIdx.x;
    const int nbase = blockIdx.x * IDX_PER_BLOCK;

    // ---------- Phase A: T[idx][r1][e1][:] = sum_r2 B[r1,i1,e1,r2] * C[r2,i2,:]
#pragma unroll
    for (int s = 0; s < 2; ++s) {
        const int task = t + s * BLOCK;         // [0, 1024)
        const int e1  = task & 3;
        const int r1  = (task >> 2) & 15;
        const int idx = task >> 6;              // [0, 16)

        const int i    = indices[nbase + idx];
        const int i0   = i / (V1 * V2);
        const int pair = i - i0 * (V1 * V2);
        const int i1   = pair / V2;
        const int i2   = pair - i1 * V2;

        // B row: 16 contiguous floats (64B); consecutive e1 -> contiguous 256B
        const float4* B4 = (const float4*)(c1 + (((size_t)r1 * V1 + i1) * 4 + e1) * RR);
        float b[RR];
#pragma unroll
        for (int q = 0; q < 4; ++q) {
            float4 v = B4[q];
            b[q * 4 + 0] = v.x; b[q * 4 + 1] = v.y;
            b[q * 4 + 2] = v.z; b[q * 4 + 3] = v.w;
        }

        // C[r2][i2][:] : float4 at stride 320 floats; same addr across the
        // wave (idx is wave-uniform per task chunk) -> L1 broadcast
        const float4* C4 = (const float4*)(c2 + (size_t)i2 * 4);
        float o0 = 0.f, o1 = 0.f, o2 = 0.f, o3 = 0.f;
#pragma unroll
        for (int r2 = 0; r2 < RR; ++r2) {
            float4 c = C4[(size_t)r2 * V2];
            o0 = fmaf(b[r2], c.x, o0);
            o1 = fmaf(b[r2], c.y, o1);
            o2 = fmaf(b[r2], c.z, o2);
            o3 = fmaf(b[r2], c.w, o3);
        }
        T[task] = make_float4(o0, o1, o2, o3);  // consecutive threads -> consecutive float4
    }

    __syncthreads();

    // ---------- Phase B: thread = (idx, e0, e1)
    const int e1  = t & 3;
    const int e0  = (t >> 2) & 7;
    const int idx = t >> 5;                     // [0, 16)
    const int n   = nbase + idx;

    const int i  = indices[n];
    const int i0 = i / (V1 * V2);

    // A[i0][e0][:] : 16 contiguous floats
    const float4* A4 = (const float4*)(c0 + ((size_t)i0 * 8 + e0) * RR);
    float a[RR];
#pragma unroll
    for (int q = 0; q < 4; ++q) {
        float4 v = A4[q];
        a[q * 4 + 0] = v.x; a[q * 4 + 1] = v.y;
        a[q * 4 + 2] = v.z; a[q * 4 + 3] = v.w;
    }

    const float4* Tb = &T[idx * 64 + e1];       // + r1*4
    float o0 = 0.f, o1 = 0.f, o2 = 0.f, o3 = 0.f;
#pragma unroll
    for (int r1 = 0; r1 < RR; ++r1) {
        float4 w = Tb[r1 * 4];
        o0 = fmaf(a[r1], w.x, o0);
        o1 = fmaf(a[r1], w.y, o1);
        o2 = fmaf(a[r1], w.z, o2);
        o3 = fmaf(a[r1], w.w, o3);
    }

    // out offset: n*128 + (e0*16 + e1*4), coalesced float4 per wave
    *(float4*)(out + (size_t)n * 128 + (e0 * 4 + e1) * 4) = make_float4(o0, o1, o2, o3);
}

extern "C" void kernel_launch(void* const* d_in, const int* in_sizes, int n_in,
                              void* d_out, int out_size, void* d_ws, size_t ws_size,
                              hipStream_t stream) {
    const int*   indices = (const int*)d_in[0];
    const float* c0      = (const float*)d_in[1];
    const float* c1      = (const float*)d_in[2];
    const float* c2      = (const float*)d_in[3];
    float*       out     = (float*)d_out;

    const int grid = NIDX / IDX_PER_BLOCK;   // 512 blocks of 512 threads
    tt_fused<<<grid, BLOCK, 0, stream>>>(indices, c0, c1, c2, out);
}